// Round 5
// baseline (76.325 us; speedup 1.0000x reference)
//
#include <hip/hip_runtime.h>
#include <stdint.h>

// Multihead_Attention on MI355X (gfx950).
// cvt6 (f32->bf16) -> proj (relu, Wo/8 folded into K cols, V stored transposed)
// -> logits GEMM -> softmax -> [PV GEMM + attn.T transpose in one launch].
// GEMM core (proj/logits/pv identical): bf16 MFMA 16x16x32, BM=BN=128, BK=64,
// 512 thr, 4-buffer LDS global_load_lds pipeline, counted s_waitcnt vmcnt(N)
// (T3+T4), 1 barrier/iter, setprio (T5), XOR chunk swizzle, XCD rect swizzle.

#define TQ 2048
#define TK 2048
#define HD 1024

#define DEVI __device__ __forceinline__

typedef __attribute__((ext_vector_type(8))) short bf16x8;
typedef __attribute__((ext_vector_type(4))) float f32x4;
typedef __attribute__((ext_vector_type(4))) unsigned short u16x4;

DEVI unsigned short f2bf(float f) {
  uint32_t u = __builtin_bit_cast(uint32_t, f);
  u += 0x7FFFu + ((u >> 16) & 1u);
  return (unsigned short)(u >> 16);
}
DEVI float bf2f(unsigned short h) {
  uint32_t u = ((uint32_t)h) << 16;
  return __builtin_bit_cast(float, u);
}
DEVI void gload_lds16(const void* g, void* l) {
  __builtin_amdgcn_global_load_lds((const __attribute__((address_space(1))) void*)g,
                                   (__attribute__((address_space(3))) void*)l,
                                   16, 0, 0);
}
template<int N> DEVI void wait_vm() { asm volatile("s_waitcnt vmcnt(%0)" :: "n"(N) : "memory"); }
DEVI void wait_lgkm0() { asm volatile("s_waitcnt lgkmcnt(0)" ::: "memory"); }
#define SBAR() __builtin_amdgcn_s_barrier()

// ---- stage one K-step tile pair (A 128x64, B 128x64 bf16) into one LDS buffer.
// 512 threads. Linear LDS dest (gload_lds requirement), source col XOR-swizzled.
DEVI void stageT(const unsigned short* __restrict__ A, const unsigned short* __restrict__ B,
                 int lda, int ldb, int k0, unsigned short* buf, int tid) {
#pragma unroll
  for (int i = 0; i < 2; i++) {              // A: 128 rows x 8 chunks = 1024 chunks
    int c = i * 512 + tid;
    int r = c >> 3;
    int cs = (c & 7) ^ (r & 7);
    gload_lds16(A + (size_t)r * lda + k0 + cs * 8, buf + c * 8);
  }
#pragma unroll
  for (int i = 0; i < 2; i++) {              // B: 128 rows x 8 chunks
    int c = i * 512 + tid;
    int r = c >> 3;
    int cs = (c & 7) ^ (r & 7);
    gload_lds16(B + (size_t)r * ldb + k0 + cs * 8, buf + 8192 + c * 8);
  }
}

// ---- one staged 64-K-step of MFMA: per wave 64x32 output (acc[4][2]).
DEVI void computeT(const unsigned short* lA, const unsigned short* lB, f32x4 (*acc)[2],
                   int wr, int wc, int l15, int hi) {
#pragma unroll
  for (int kk = 0; kk < 2; kk++) {
    bf16x8 af[4], bfr[2];
#pragma unroll
    for (int f = 0; f < 4; f++) {
      int ra = wr * 64 + f * 16 + l15;
      int ca = (kk * 4 + hi) ^ (ra & 7);
      af[f] = *(const bf16x8*)(lA + ra * 64 + ca * 8);
    }
#pragma unroll
    for (int f = 0; f < 2; f++) {
      int rb = wc * 32 + f * 16 + l15;
      int cb = (kk * 4 + hi) ^ (rb & 7);
      bfr[f] = *(const bf16x8*)(lB + rb * 64 + cb * 8);
    }
#pragma unroll
    for (int fm = 0; fm < 4; fm++)
#pragma unroll
      for (int fn = 0; fn < 2; fn++)
        acc[fm][fn] = __builtin_amdgcn_mfma_f32_16x16x32_bf16(af[fm], bfr[fn], acc[fm][fn], 0, 0, 0);
  }
}

// ---- gload_lds pipeline: 4 LDS buffers, depth-2 in flight, 1 barrier/iter.
// Ledger: reads of buf t guarded by [wait_vm -> SBAR]. stage(t+3) targets buf
// (t+3)&3 != bufs t,t+1,t+2 (being read / pending); WAR vs compute(t-1)'s reads of
// buf (t-1)&3 is safe: every wave's lgkm0 precedes SBAR(t), draining its ds_reads.
template<int NKT>
DEVI void mfma_pipeline(const unsigned short* __restrict__ A, const unsigned short* __restrict__ B,
                        int lda, int ldb, unsigned short* lds, f32x4 (*acc)[2]) {
  constexpr int LPS = 4;                     // loads per stage per thread
  constexpr int BSTR = 16384;                // buffer stride in shorts (64 KB/2... 32 KB)
  const int tid = threadIdx.x;
  const int lane = tid & 63, wave = tid >> 6;
  const int l15 = lane & 15, hi = lane >> 4;
  const int wr = wave >> 2, wc = wave & 3;

#pragma unroll
  for (int i = 0; i < 4; i++)
#pragma unroll
    for (int j = 0; j < 2; j++) acc[i][j] = (f32x4)(0.0f);

#pragma unroll
  for (int s = 0; s < 3; s++) stageT(A, B, lda, ldb, s * 64, lds + s * BSTR, tid);

#pragma unroll 1
  for (int t = 0; t < NKT; ++t) {
    if (t < NKT - 2) wait_vm<2 * LPS>();
    else if (t == NKT - 2) wait_vm<LPS>();
    else wait_vm<0>();
    SBAR();                                   // buf t ready on every wave
    unsigned short* buf = lds + (t & 3) * BSTR;
    __builtin_amdgcn_s_setprio(1);
    computeT(buf, buf + 8192, acc, wr, wc, l15, hi);
    __builtin_amdgcn_s_setprio(0);
    wait_lgkm0();                             // my ds_reads drained (WAR safety)
    if (t + 3 < NKT) stageT(A, B, lda, ldb, (t + 3) * 64, lds + ((t + 3) & 3) * BSTR, tid);
  }
}

// ------------- batched projection: relu(X @ W^T + b), BN=128, 384 blocks -----------
__global__ __launch_bounds__(512)
void gemm_proj(const unsigned short* __restrict__ Qb, const unsigned short* __restrict__ Kb,
               const unsigned short* __restrict__ Vb,
               const unsigned short* __restrict__ Wqb, const unsigned short* __restrict__ Wkb,
               const unsigned short* __restrict__ Wvb,
               const float* __restrict__ bq, const float* __restrict__ bk,
               const float* __restrict__ bv, const float* __restrict__ Wo,
               unsigned short* __restrict__ Ql, unsigned short* __restrict__ Ks,
               unsigned short* __restrict__ VT) {
  __shared__ __align__(16) unsigned short lds[4 * 16384];  // 128 KB
  const int bid = blockIdx.x;
  const int x = bid & 7, j = bid >> 3;     // XCD, index within (48 per XCD)
  const int z = j >> 4;                    // 16 tiles per z per XCD
  const int jj = j & 15;
  const int bm = (x & 3) * 4 + (jj >> 2);  // [0,16)
  const int bn = (x >> 2) * 4 + (jj & 3);  // [0,8)

  const unsigned short* A = (z == 0) ? Qb : (z == 1) ? Kb : Vb;
  const unsigned short* B = (z == 0) ? Wqb : (z == 1) ? Wkb : Wvb;
  const float* bias = (z == 0) ? bq : (z == 1) ? bk : bv;

  f32x4 acc[4][2];
  mfma_pipeline<16>(A + (size_t)bm * 128 * HD, B + (size_t)bn * 128 * HD, HD, HD, lds, acc);

  const int tid = threadIdx.x;
  const int lane = tid & 63, wave = tid >> 6;
  const int wr = wave >> 2, wc = wave & 3;
  const int l15 = lane & 15, hi = lane >> 4;
  const int row0 = bm * 128 + wr * 64;
  const int col0 = bn * 128 + wc * 32;

#pragma unroll
  for (int fm = 0; fm < 4; fm++)
#pragma unroll
    for (int fn = 0; fn < 2; fn++) {
      int cg = col0 + fn * 16 + l15;
      int rg = row0 + fm * 16 + hi * 4;
      float b = bias[cg];
      if (z == 2) {
        u16x4 o;
#pragma unroll
        for (int i = 0; i < 4; i++) o[i] = f2bf(fmaxf(acc[fm][fn][i] + b, 0.0f));
        *(u16x4*)(VT + (size_t)cg * TK + rg) = o;   // transposed store for PV B operand
      } else if (z == 1) {
        float s = 0.125f * Wo[cg >> 6];             // fold Wo/sqrt(64) into K columns
#pragma unroll
        for (int i = 0; i < 4; i++)
          Ks[(size_t)(rg + i) * HD + cg] = f2bf(fmaxf(acc[fm][fn][i] + b, 0.0f) * s);
      } else {
#pragma unroll
        for (int i = 0; i < 4; i++)
          Ql[(size_t)(rg + i) * HD + cg] = f2bf(fmaxf(acc[fm][fn][i] + b, 0.0f));
      }
    }
}

// ------------- logits = Ql @ Ks^T : [2048,2048] f32, 256 blocks --------------------
__global__ __launch_bounds__(512)
void gemm_logits(const unsigned short* __restrict__ Ql, const unsigned short* __restrict__ Ks,
                 float* __restrict__ C) {
  __shared__ __align__(16) unsigned short lds[4 * 16384];  // 128 KB
  const int bid = blockIdx.x;
  const int x = bid & 7, j = bid >> 3;     // 32 per XCD
  const int bm = (x & 3) * 4 + (j >> 3);   // [0,16)
  const int bn = (x >> 2) * 8 + (j & 7);   // [0,16)

  f32x4 acc[4][2];
  mfma_pipeline<16>(Ql + (size_t)bm * 128 * HD, Ks + (size_t)bn * 128 * HD, HD, HD, lds, acc);

  const int tid = threadIdx.x;
  const int lane = tid & 63, wave = tid >> 6;
  const int wr = wave >> 2, wc = wave & 3;
  const int l15 = lane & 15, hi = lane >> 4;
  const int row0 = bm * 128 + wr * 64;
  const int col0 = bn * 128 + wc * 32;
#pragma unroll
  for (int fm = 0; fm < 4; fm++)
#pragma unroll
    for (int fn = 0; fn < 2; fn++) {
      int cg = col0 + fn * 16 + l15;
      int rg = row0 + fm * 16 + hi * 4;
#pragma unroll
      for (int i = 0; i < 4; i++)
        C[(size_t)(rg + i) * TK + cg] = acc[fm][fn][i];
    }
}

// ------------- PV GEMM (full K=2048, 128 blocks) + attn.T transpose (1024 blocks) --
__global__ __launch_bounds__(512)
void pv_and_transpose(const unsigned short* __restrict__ attnb, const unsigned short* __restrict__ VT,
                      float* __restrict__ outp, float* __restrict__ attnT) {
  __shared__ __align__(16) unsigned short lds[4 * 16384];  // 128 KB
  const int bid = blockIdx.x;
  const int tid = threadIdx.x;
  if (bid < 128) {
    const int x = bid & 7, j = bid >> 3;    // 16 per XCD
    const int bm = (x & 3) * 4 + (j >> 2);  // [0,16)
    const int bn = (x >> 2) * 4 + (j & 3);  // [0,8)
    f32x4 acc[4][2];
    mfma_pipeline<32>(attnb + (size_t)bm * 128 * TK, VT + (size_t)bn * 128 * TK,
                      TK, TK, lds, acc);
    const int lane = tid & 63, wave = tid >> 6;
    const int wr = wave >> 2, wc = wave & 3;
    const int l15 = lane & 15, hi = lane >> 4;
    const int row0 = bm * 128 + wr * 64;
    const int col0 = bn * 128 + wc * 32;
#pragma unroll
    for (int fm = 0; fm < 4; fm++)
#pragma unroll
      for (int fn = 0; fn < 2; fn++) {
        int cg = col0 + fn * 16 + l15;
        int rg = row0 + fm * 16 + hi * 4;
#pragma unroll
        for (int i = 0; i < 4; i++)
          outp[(size_t)(rg + i) * HD + cg] = acc[fm][fn][i];
      }
  } else {
    // transpose: bf16 attn [TQ][TK] tile (64x64) -> f32 attn.T [TK][TQ]
    unsigned short (*tile)[68] = reinterpret_cast<unsigned short (*)[68]>(lds);
    const int q0 = bid - 128;
    const int tr = (q0 >> 5) * 64;   // source row block
    const int tc = (q0 & 31) * 64;   // source col block
#pragma unroll
    for (int i = 0; i < 2; i++) {
      int q = i * 512 + tid;
      int r = q >> 4;
      int c4 = (q & 15) * 4;
      u16x4 v = *(const u16x4*)(attnb + (size_t)(tr + r) * TK + tc + c4);
      *(u16x4*)(&tile[r][c4]) = v;
    }
    __syncthreads();
#pragma unroll
    for (int i = 0; i < 2; i++) {
      int q = i * 512 + tid;
      int c = q >> 4;
      int r4 = (q & 15) * 4;
      f32x4 o;
#pragma unroll
      for (int jx = 0; jx < 4; jx++) o[jx] = bf2f(tile[r4 + jx][c]);
      *(f32x4*)(attnT + (size_t)(tc + c) * TQ + tr + r4) = o;
    }
  }
}

// ------------- row softmax over 2048 logits -> bf16 attn ---------------------------
__global__ __launch_bounds__(256)
void softmax_k(const float* __restrict__ logits, unsigned short* __restrict__ attnb) {
  const int row = blockIdx.x;
  const int tid = threadIdx.x;
  const int lane = tid & 63;
  const int wave = tid >> 6;
  const float* lr = logits + (size_t)row * TK;

  f32x4 v0 = *(const f32x4*)(lr + tid * 8);
  f32x4 v1 = *(const f32x4*)(lr + tid * 8 + 4);
  float x[8];
#pragma unroll
  for (int j = 0; j < 4; j++) { x[j] = v0[j]; x[4 + j] = v1[j]; }

  float m = x[0];
#pragma unroll
  for (int j = 1; j < 8; j++) m = fmaxf(m, x[j]);
  for (int o = 32; o > 0; o >>= 1) m = fmaxf(m, __shfl_xor(m, o));
  __shared__ float redm[4], reds[4];
  if (lane == 0) redm[wave] = m;
  __syncthreads();
  m = fmaxf(fmaxf(redm[0], redm[1]), fmaxf(redm[2], redm[3]));

  const float L2E = 1.44269504088896341f;
  float e[8];
  float s = 0.0f;
#pragma unroll
  for (int j = 0; j < 8; j++) { e[j] = exp2f((x[j] - m) * L2E); s += e[j]; }
  for (int o = 32; o > 0; o >>= 1) s += __shfl_xor(s, o);
  if (lane == 0) reds[wave] = s;
  __syncthreads();
  s = reds[0] + reds[1] + reds[2] + reds[3];
  float inv = 1.0f / s;

  unsigned short* ar = attnb + (size_t)row * TK;
  u16x4 o0, o1;
#pragma unroll
  for (int j = 0; j < 4; j++) { o0[j] = f2bf(e[j] * inv); o1[j] = f2bf(e[4 + j] * inv); }
  *(u16x4*)(ar + tid * 8) = o0;
  *(u16x4*)(ar + tid * 8 + 4) = o1;
}

// ------------- all six f32 -> bf16 converts in one launch --------------------------
__global__ __launch_bounds__(256)
void cvt6(const float* __restrict__ Q, const float* __restrict__ K, const float* __restrict__ V,
          const float* __restrict__ Wq, const float* __restrict__ Wk, const float* __restrict__ Wv,
          unsigned short* __restrict__ Qb, unsigned short* __restrict__ Kb,
          unsigned short* __restrict__ Vb, unsigned short* __restrict__ Wqb,
          unsigned short* __restrict__ Wkb, unsigned short* __restrict__ Wvb) {
  const int y = blockIdx.y;
  const float* s;
  unsigned short* d;
  int n4;
  switch (y) {
    case 0: s = Q;  d = Qb;  n4 = TQ * HD / 4; break;
    case 1: s = K;  d = Kb;  n4 = TK * HD / 4; break;
    case 2: s = V;  d = Vb;  n4 = TK * HD / 4; break;
    case 3: s = Wq; d = Wqb; n4 = HD * HD / 4; break;
    case 4: s = Wk; d = Wkb; n4 = HD * HD / 4; break;
    default: s = Wv; d = Wvb; n4 = HD * HD / 4; break;
  }
  int i = blockIdx.x * 256 + threadIdx.x;
  if (i < n4) {
    f32x4 v = *(const f32x4*)(s + i * 4);
    u16x4 o;
#pragma unroll
    for (int j = 0; j < 4; j++) o[j] = f2bf(v[j]);
    *(u16x4*)(d + i * 4) = o;
  }
}

extern "C" void kernel_launch(void* const* d_in, const int* in_sizes, int n_in,
                              void* d_out, int out_size, void* d_ws, size_t ws_size,
                              hipStream_t stream) {
  const float* Q  = (const float*)d_in[0];
  const float* K  = (const float*)d_in[1];
  const float* V  = (const float*)d_in[2];
  const float* Wq = (const float*)d_in[3];
  const float* bq = (const float*)d_in[4];
  const float* Wk = (const float*)d_in[5];
  const float* bk = (const float*)d_in[6];
  const float* Wv = (const float*)d_in[7];
  const float* bv = (const float*)d_in[8];
  const float* Wo = (const float*)d_in[9];
  // bo unused: softmax shift-invariant.

  uint8_t* w = (uint8_t*)d_ws;
  unsigned short* Qb  = (unsigned short*)(w + 0);            // 4 MB
  unsigned short* Kb  = (unsigned short*)(w + 4194304);      // 4 MB
  unsigned short* Vb  = (unsigned short*)(w + 8388608);      // 4 MB
  unsigned short* Wqb = (unsigned short*)(w + 12582912);     // 2 MB
  unsigned short* Wkb = (unsigned short*)(w + 14680064);     // 2 MB
  unsigned short* Wvb = (unsigned short*)(w + 16777216);     // 2 MB
  unsigned short* Ql  = (unsigned short*)(w + 18874368);     // 4 MB
  unsigned short* Ks  = (unsigned short*)(w + 23068672);     // 4 MB
  unsigned short* VT  = (unsigned short*)(w + 27262976);     // 4 MB
  float*          logits = (float*)(w + 31457280);           // 16 MB
  unsigned short* attnb  = (unsigned short*)(w + 48234496);  // 8 MB
  // total 56,623,104 bytes

  float* outp  = (float*)d_out;              // [2048][1024]
  float* attnT = outp + (size_t)TQ * HD;     // [2048][2048]

  cvt6<<<dim3(2048, 6), dim3(256), 0, stream>>>(Q, K, V, Wq, Wk, Wv, Qb, Kb, Vb, Wqb, Wkb, Wvb);

  // projections: M=2048, N=1024, K=1024, z in {Q,K,V}; 384 blocks (BN=128)
  gemm_proj<<<dim3(384), dim3(512), 0, stream>>>(Qb, Kb, Vb, Wqb, Wkb, Wvb,
                                                 bq, bk, bv, Wo, Ql, Ks, VT);

  // logits: M=2048, N=2048, K=1024; 256 blocks
  gemm_logits<<<dim3(256), dim3(512), 0, stream>>>(Ql, Ks, logits);

  softmax_k<<<dim3(TQ), dim3(256), 0, stream>>>(logits, attnb);

  // PV (M=2048,N=1024,K=2048; 128 blocks) + transpose (1024 blocks), one launch
  pv_and_transpose<<<dim3(1152), dim3(512), 0, stream>>>(attnb, VT, outp, attnT);
}

// Round 6
// 74.011 us; speedup vs baseline: 1.0313x; 1.0313x over previous
//
#include <hip/hip_runtime.h>
#include <stdint.h>

// Multihead_Attention on MI355X (gfx950).
// cvt6 (f32->bf16) -> proj (relu, Wo/8 folded into K cols, V stored transposed via
// LDS-transpose epilogue) -> logits GEMM -> softmax -> [PV GEMM + attn.T transpose].
// GEMM core (shared): bf16 MFMA 16x16x32, BM=BN=128, BK=64, 512 thr, 2-buffer LDS
// (64 KB -> 2 blocks/CU), global_load_lds w16, counted s_waitcnt vmcnt(4) (T3+T4),
// 2 barriers/iter, setprio (T5), XOR chunk swizzle, XCD rect swizzle.

#define TQ 2048
#define TK 2048
#define HD 1024

#define DEVI __device__ __forceinline__

typedef __attribute__((ext_vector_type(8))) short bf16x8;
typedef __attribute__((ext_vector_type(4))) float f32x4;
typedef __attribute__((ext_vector_type(4))) unsigned short u16x4;

DEVI unsigned short f2bf(float f) {
  uint32_t u = __builtin_bit_cast(uint32_t, f);
  u += 0x7FFFu + ((u >> 16) & 1u);
  return (unsigned short)(u >> 16);
}
DEVI float bf2f(unsigned short h) {
  uint32_t u = ((uint32_t)h) << 16;
  return __builtin_bit_cast(float, u);
}
DEVI void gload_lds16(const void* g, void* l) {
  __builtin_amdgcn_global_load_lds((const __attribute__((address_space(1))) void*)g,
                                   (__attribute__((address_space(3))) void*)l,
                                   16, 0, 0);
}
template<int N> DEVI void wait_vm() { asm volatile("s_waitcnt vmcnt(%0)" :: "n"(N) : "memory"); }
DEVI void wait_lgkm0() { asm volatile("s_waitcnt lgkmcnt(0)" ::: "memory"); }
#define SBAR() __builtin_amdgcn_s_barrier()

// ---- stage one K-step tile pair (A 128x64, B 128x64 bf16) into one LDS buffer.
// 512 threads, 4 gload_lds instr/wave. Linear LDS dest, source col XOR-swizzled.
DEVI void stageT(const unsigned short* __restrict__ A, const unsigned short* __restrict__ B,
                 int lda, int ldb, int k0, unsigned short* buf, int tid) {
#pragma unroll
  for (int i = 0; i < 2; i++) {              // A: 128 rows x 8 chunks = 1024 chunks
    int c = i * 512 + tid;
    int r = c >> 3;
    int cs = (c & 7) ^ (r & 7);
    gload_lds16(A + (size_t)r * lda + k0 + cs * 8, buf + c * 8);
  }
#pragma unroll
  for (int i = 0; i < 2; i++) {              // B: 128 rows x 8 chunks
    int c = i * 512 + tid;
    int r = c >> 3;
    int cs = (c & 7) ^ (r & 7);
    gload_lds16(B + (size_t)r * ldb + k0 + cs * 8, buf + 8192 + c * 8);
  }
}

// ---- one staged 64-K-step of MFMA: per wave 64x32 output (acc[4][2]).
DEVI void computeT(const unsigned short* lA, const unsigned short* lB, f32x4 (*acc)[2],
                   int wr, int wc, int l15, int hi) {
#pragma unroll
  for (int kk = 0; kk < 2; kk++) {
    bf16x8 af[4], bfr[2];
#pragma unroll
    for (int f = 0; f < 4; f++) {
      int ra = wr * 64 + f * 16 + l15;
      int ca = (kk * 4 + hi) ^ (ra & 7);
      af[f] = *(const bf16x8*)(lA + ra * 64 + ca * 8);
    }
#pragma unroll
    for (int f = 0; f < 2; f++) {
      int rb = wc * 32 + f * 16 + l15;
      int cb = (kk * 4 + hi) ^ (rb & 7);
      bfr[f] = *(const bf16x8*)(lB + rb * 64 + cb * 8);
    }
#pragma unroll
    for (int fm = 0; fm < 4; fm++)
#pragma unroll
      for (int fn = 0; fn < 2; fn++)
        acc[fm][fn] = __builtin_amdgcn_mfma_f32_16x16x32_bf16(af[fm], bfr[fn], acc[fm][fn], 0, 0, 0);
  }
}

// ---- 2-buffer pipeline, counted vmcnt, 2 barriers/iter, 64 KB LDS (2 blocks/CU).
// Ledger: wave X reads buf[t&1] after SBAR#1; every wave Y passed its wait_vm<4>
// (stage(t) loads retired) before SBAR#1 -> cross-wave RAW safe. stage(t+2) writes
// buf[t&1] only after SBAR#2, which every wave reaches only after its lgkm0
// (compute(t) ds_reads drained) -> WAR safe. vmcnt: at iter t, outstanding =
// {stage(t)?, stage(t+1)}; <=4 guarantees stage(t) landed.
template<int NKT>
DEVI void mfma_pipeline(const unsigned short* __restrict__ A, const unsigned short* __restrict__ B,
                        int lda, int ldb, unsigned short* lds, f32x4 (*acc)[2]) {
  const int tid = threadIdx.x;
  const int lane = tid & 63, wave = tid >> 6;
  const int l15 = lane & 15, hi = lane >> 4;
  const int wr = wave >> 2, wc = wave & 3;

#pragma unroll
  for (int i = 0; i < 4; i++)
#pragma unroll
    for (int j = 0; j < 2; j++) acc[i][j] = (f32x4)(0.0f);

  stageT(A, B, lda, ldb, 0, lds, tid);
  stageT(A, B, lda, ldb, 64, lds + 16384, tid);

#pragma unroll 1
  for (int t = 0; t < NKT; ++t) {
    if (t < NKT - 1) wait_vm<4>();
    else wait_vm<0>();
    SBAR();                                   // buf t ready on every wave
    unsigned short* buf = lds + (t & 1) * 16384;
    __builtin_amdgcn_s_setprio(1);
    computeT(buf, buf + 8192, acc, wr, wc, l15, hi);
    __builtin_amdgcn_s_setprio(0);
    wait_lgkm0();                             // my ds_reads drained
    SBAR();                                   // all waves done reading buf
    if (t + 2 < NKT) stageT(A, B, lda, ldb, (t + 2) * 64, buf, tid);
  }
}

// ------------- batched projection: relu(X @ W^T + b), 384 blocks -------------------
__global__ __launch_bounds__(512, 4)
void gemm_proj(const unsigned short* __restrict__ Qb, const unsigned short* __restrict__ Kb,
               const unsigned short* __restrict__ Vb,
               const unsigned short* __restrict__ Wqb, const unsigned short* __restrict__ Wkb,
               const unsigned short* __restrict__ Wvb,
               const float* __restrict__ bq, const float* __restrict__ bk,
               const float* __restrict__ bv, const float* __restrict__ Wo,
               unsigned short* __restrict__ Ql, unsigned short* __restrict__ Ks,
               unsigned short* __restrict__ VT) {
  __shared__ __align__(16) unsigned short lds[2 * 16384];  // 64 KB
  const int bid = blockIdx.x;
  const int x = bid & 7, j = bid >> 3;       // XCD, index within (48 per XCD)
  const int bmz = x * 6 + (j >> 3);          // [0,48): 6 consecutive M-panels per XCD
  const int bn = j & 7;                      // [0,8) full N per XCD
  const int z = bmz >> 4;                    // matrix select
  const int bm = bmz & 15;                   // [0,16)

  const unsigned short* A = (z == 0) ? Qb : (z == 1) ? Kb : Vb;
  const unsigned short* B = (z == 0) ? Wqb : (z == 1) ? Wkb : Wvb;
  const float* bias = (z == 0) ? bq : (z == 1) ? bk : bv;

  f32x4 acc[4][2];
  mfma_pipeline<16>(A + (size_t)bm * 128 * HD, B + (size_t)bn * 128 * HD, HD, HD, lds, acc);

  const int tid = threadIdx.x;
  const int lane = tid & 63, wave = tid >> 6;
  const int wr = wave >> 2, wc = wave & 3;
  const int l15 = lane & 15, hi = lane >> 4;
  const int row0 = bm * 128 + wr * 64;
  const int col0 = bn * 128 + wc * 32;

  if (z == 2) {
    // LDS-transpose the 128x128 output tile, then coalesced VT row stores.
    unsigned short (*T)[132] = reinterpret_cast<unsigned short (*)[132]>(lds);
#pragma unroll
    for (int fm = 0; fm < 4; fm++)
#pragma unroll
      for (int fn = 0; fn < 2; fn++) {
        int cl = wc * 32 + fn * 16 + l15;     // local col
        float b = bias[bn * 128 + cl];
#pragma unroll
        for (int i = 0; i < 4; i++)
          T[cl][wr * 64 + fm * 16 + hi * 4 + i] = f2bf(fmaxf(acc[fm][fn][i] + b, 0.0f));
      }
    __syncthreads();
#pragma unroll
    for (int i = 0; i < 8; i++) {
      int h = i * 512 + tid;                  // 4096 u16x4 chunks
      int c = h >> 5;                         // [0,128) local col -> VT row
      int rq = h & 31;                        // quad within row
      u16x4 v = *(const u16x4*)(&T[c][rq * 4]);
      *(u16x4*)(VT + (size_t)(bn * 128 + c) * TK + bm * 128 + rq * 4) = v;
    }
  } else {
#pragma unroll
    for (int fm = 0; fm < 4; fm++)
#pragma unroll
      for (int fn = 0; fn < 2; fn++) {
        int cg = col0 + fn * 16 + l15;
        int rg = row0 + fm * 16 + hi * 4;
        float b = bias[cg];
        if (z == 1) {
          float s = 0.125f * Wo[cg >> 6];     // fold Wo/sqrt(64) into K columns
#pragma unroll
          for (int i = 0; i < 4; i++)
            Ks[(size_t)(rg + i) * HD + cg] = f2bf(fmaxf(acc[fm][fn][i] + b, 0.0f) * s);
        } else {
#pragma unroll
          for (int i = 0; i < 4; i++)
            Ql[(size_t)(rg + i) * HD + cg] = f2bf(fmaxf(acc[fm][fn][i] + b, 0.0f));
        }
      }
  }
}

// ------------- logits = Ql @ Ks^T : [2048,2048] f32, 256 blocks --------------------
__global__ __launch_bounds__(512, 4)
void gemm_logits(const unsigned short* __restrict__ Ql, const unsigned short* __restrict__ Ks,
                 float* __restrict__ C) {
  __shared__ __align__(16) unsigned short lds[2 * 16384];  // 64 KB
  const int bid = blockIdx.x;
  const int x = bid & 7, j = bid >> 3;     // 32 per XCD
  const int bm = (x & 3) * 4 + (j >> 3);   // [0,16)
  const int bn = (x >> 2) * 8 + (j & 7);   // [0,16)

  f32x4 acc[4][2];
  mfma_pipeline<16>(Ql + (size_t)bm * 128 * HD, Ks + (size_t)bn * 128 * HD, HD, HD, lds, acc);

  const int tid = threadIdx.x;
  const int lane = tid & 63, wave = tid >> 6;
  const int wr = wave >> 2, wc = wave & 3;
  const int l15 = lane & 15, hi = lane >> 4;
  const int row0 = bm * 128 + wr * 64;
  const int col0 = bn * 128 + wc * 32;
#pragma unroll
  for (int fm = 0; fm < 4; fm++)
#pragma unroll
    for (int fn = 0; fn < 2; fn++) {
      int cg = col0 + fn * 16 + l15;
      int rg = row0 + fm * 16 + hi * 4;
#pragma unroll
      for (int i = 0; i < 4; i++)
        C[(size_t)(rg + i) * TK + cg] = acc[fm][fn][i];
    }
}

// ------------- PV GEMM (full K=2048, 128 blocks) + attn.T transpose (1024 blocks) --
__global__ __launch_bounds__(512, 4)
void pv_and_transpose(const unsigned short* __restrict__ attnb, const unsigned short* __restrict__ VT,
                      float* __restrict__ outp, float* __restrict__ attnT) {
  __shared__ __align__(16) unsigned short lds[2 * 16384];  // 64 KB
  const int bid = blockIdx.x;
  const int tid = threadIdx.x;
  if (bid < 128) {
    const int x = bid & 7, j = bid >> 3;    // 16 per XCD
    const int bm = (x & 3) * 4 + (j >> 2);  // [0,16)
    const int bn = (x >> 2) * 4 + (j & 3);  // [0,8)
    f32x4 acc[4][2];
    mfma_pipeline<32>(attnb + (size_t)bm * 128 * TK, VT + (size_t)bn * 128 * TK,
                      TK, TK, lds, acc);
    const int lane = tid & 63, wave = tid >> 6;
    const int wr = wave >> 2, wc = wave & 3;
    const int l15 = lane & 15, hi = lane >> 4;
    const int row0 = bm * 128 + wr * 64;
    const int col0 = bn * 128 + wc * 32;
#pragma unroll
    for (int fm = 0; fm < 4; fm++)
#pragma unroll
      for (int fn = 0; fn < 2; fn++) {
        int cg = col0 + fn * 16 + l15;
        int rg = row0 + fm * 16 + hi * 4;
#pragma unroll
        for (int i = 0; i < 4; i++)
          outp[(size_t)(rg + i) * HD + cg] = acc[fm][fn][i];
      }
  } else {
    // transpose: bf16 attn [TQ][TK] tile (64x64) -> f32 attn.T [TK][TQ]
    unsigned short (*tile)[68] = reinterpret_cast<unsigned short (*)[68]>(lds);
    const int q0 = bid - 128;
    const int tr = (q0 >> 5) * 64;   // source row block
    const int tc = (q0 & 31) * 64;   // source col block
#pragma unroll
    for (int i = 0; i < 2; i++) {
      int q = i * 512 + tid;
      int r = q >> 4;
      int c4 = (q & 15) * 4;
      u16x4 v = *(const u16x4*)(attnb + (size_t)(tr + r) * TK + tc + c4);
      *(u16x4*)(&tile[r][c4]) = v;
    }
    __syncthreads();
#pragma unroll
    for (int i = 0; i < 2; i++) {
      int q = i * 512 + tid;
      int c = q >> 4;
      int r4 = (q & 15) * 4;
      f32x4 o;
#pragma unroll
      for (int jx = 0; jx < 4; jx++) o[jx] = bf2f(tile[r4 + jx][c]);
      *(f32x4*)(attnT + (size_t)(tc + c) * TQ + tr + r4) = o;
    }
  }
}

// ------------- row softmax over 2048 logits -> bf16 attn ---------------------------
__global__ __launch_bounds__(256)
void softmax_k(const float* __restrict__ logits, unsigned short* __restrict__ attnb) {
  const int row = blockIdx.x;
  const int tid = threadIdx.x;
  const int lane = tid & 63;
  const int wave = tid >> 6;
  const float* lr = logits + (size_t)row * TK;

  f32x4 v0 = *(const f32x4*)(lr + tid * 8);
  f32x4 v1 = *(const f32x4*)(lr + tid * 8 + 4);
  float x[8];
#pragma unroll
  for (int j = 0; j < 4; j++) { x[j] = v0[j]; x[4 + j] = v1[j]; }

  float m = x[0];
#pragma unroll
  for (int j = 1; j < 8; j++) m = fmaxf(m, x[j]);
  for (int o = 32; o > 0; o >>= 1) m = fmaxf(m, __shfl_xor(m, o));
  __shared__ float redm[4], reds[4];
  if (lane == 0) redm[wave] = m;
  __syncthreads();
  m = fmaxf(fmaxf(redm[0], redm[1]), fmaxf(redm[2], redm[3]));

  const float L2E = 1.44269504088896341f;
  float e[8];
  float s = 0.0f;
#pragma unroll
  for (int j = 0; j < 8; j++) { e[j] = exp2f((x[j] - m) * L2E); s += e[j]; }
  for (int o = 32; o > 0; o >>= 1) s += __shfl_xor(s, o);
  if (lane == 0) reds[wave] = s;
  __syncthreads();
  s = reds[0] + reds[1] + reds[2] + reds[3];
  float inv = 1.0f / s;

  unsigned short* ar = attnb + (size_t)row * TK;
  u16x4 o0, o1;
#pragma unroll
  for (int j = 0; j < 4; j++) { o0[j] = f2bf(e[j] * inv); o1[j] = f2bf(e[4 + j] * inv); }
  *(u16x4*)(ar + tid * 8) = o0;
  *(u16x4*)(ar + tid * 8 + 4) = o1;
}

// ------------- all six f32 -> bf16 converts in one launch --------------------------
__global__ __launch_bounds__(256)
void cvt6(const float* __restrict__ Q, const float* __restrict__ K, const float* __restrict__ V,
          const float* __restrict__ Wq, const float* __restrict__ Wk, const float* __restrict__ Wv,
          unsigned short* __restrict__ Qb, unsigned short* __restrict__ Kb,
          unsigned short* __restrict__ Vb, unsigned short* __restrict__ Wqb,
          unsigned short* __restrict__ Wkb, unsigned short* __restrict__ Wvb) {
  const int y = blockIdx.y;
  const float* s;
  unsigned short* d;
  int n4;
  switch (y) {
    case 0: s = Q;  d = Qb;  n4 = TQ * HD / 4; break;
    case 1: s = K;  d = Kb;  n4 = TK * HD / 4; break;
    case 2: s = V;  d = Vb;  n4 = TK * HD / 4; break;
    case 3: s = Wq; d = Wqb; n4 = HD * HD / 4; break;
    case 4: s = Wk; d = Wkb; n4 = HD * HD / 4; break;
    default: s = Wv; d = Wvb; n4 = HD * HD / 4; break;
  }
  int i = blockIdx.x * 256 + threadIdx.x;
  if (i < n4) {
    f32x4 v = *(const f32x4*)(s + i * 4);
    u16x4 o;
#pragma unroll
    for (int j = 0; j < 4; j++) o[j] = f2bf(v[j]);
    *(u16x4*)(d + i * 4) = o;
  }
}

extern "C" void kernel_launch(void* const* d_in, const int* in_sizes, int n_in,
                              void* d_out, int out_size, void* d_ws, size_t ws_size,
                              hipStream_t stream) {
  const float* Q  = (const float*)d_in[0];
  const float* K  = (const float*)d_in[1];
  const float* V  = (const float*)d_in[2];
  const float* Wq = (const float*)d_in[3];
  const float* bq = (const float*)d_in[4];
  const float* Wk = (const float*)d_in[5];
  const float* bk = (const float*)d_in[6];
  const float* Wv = (const float*)d_in[7];
  const float* bv = (const float*)d_in[8];
  const float* Wo = (const float*)d_in[9];
  // bo unused: softmax shift-invariant.

  uint8_t* w = (uint8_t*)d_ws;
  unsigned short* Qb  = (unsigned short*)(w + 0);            // 4 MB
  unsigned short* Kb  = (unsigned short*)(w + 4194304);      // 4 MB
  unsigned short* Vb  = (unsigned short*)(w + 8388608);      // 4 MB
  unsigned short* Wqb = (unsigned short*)(w + 12582912);     // 2 MB
  unsigned short* Wkb = (unsigned short*)(w + 14680064);     // 2 MB
  unsigned short* Wvb = (unsigned short*)(w + 16777216);     // 2 MB
  unsigned short* Ql  = (unsigned short*)(w + 18874368);     // 4 MB
  unsigned short* Ks  = (unsigned short*)(w + 23068672);     // 4 MB
  unsigned short* VT  = (unsigned short*)(w + 27262976);     // 4 MB
  float*          logits = (float*)(w + 31457280);           // 16 MB
  unsigned short* attnb  = (unsigned short*)(w + 48234496);  // 8 MB
  // total 56,623,104 bytes

  float* outp  = (float*)d_out;              // [2048][1024]
  float* attnT = outp + (size_t)TQ * HD;     // [2048][2048]

  cvt6<<<dim3(2048, 6), dim3(256), 0, stream>>>(Q, K, V, Wq, Wk, Wv, Qb, Kb, Vb, Wqb, Wkb, Wvb);

  // projections: M=2048, N=1024, K=1024, z in {Q,K,V}; 384 blocks, 2 blocks/CU
  gemm_proj<<<dim3(384), dim3(512), 0, stream>>>(Qb, Kb, Vb, Wqb, Wkb, Wvb,
                                                 bq, bk, bv, Wo, Ql, Ks, VT);

  // logits: M=2048, N=2048, K=1024; 256 blocks
  gemm_logits<<<dim3(256), dim3(512), 0, stream>>>(Ql, Ks, logits);

  softmax_k<<<dim3(TQ), dim3(256), 0, stream>>>(logits, attnb);

  // PV (M=2048,N=1024,K=2048; 128 blocks) + transpose (1024 blocks), one launch
  pv_and_transpose<<<dim3(1152), dim3(512), 0, stream>>>(attnb, VT, outp, attnT);
}